// Round 1
// baseline (680.511 us; speedup 1.0000x reference)
//
#include <hip/hip_runtime.h>
#include <hip/hip_bf16.h>

// Problem constants (reference: n=8192, d=1024, T=0.2, eps=1e-8)
#define NN 8192
#define DD 1024

typedef __attribute__((ext_vector_type(8))) short bf16x8;   // 8 bf16 = 4 VGPRs
typedef __attribute__((ext_vector_type(4))) float floatx4;  // MFMA C/D frag

__device__ __forceinline__ void load_lds16(const void* g, void* l) {
  // async global->LDS, 16B per lane; LDS dest = wave-uniform base + lane*16
  __builtin_amdgcn_global_load_lds(
      (const __attribute__((address_space(1))) unsigned int*)g,
      (__attribute__((address_space(3))) unsigned int*)l, 16, 0, 0);
}

__device__ __forceinline__ unsigned short f2bf(float x) {
  // round-to-nearest-even fp32 -> bf16
  unsigned int u = __float_as_uint(x);
  u = (u + 0x7fffu + ((u >> 16) & 1u)) >> 16;
  return (unsigned short)u;
}

// Kernel 1: row L2-normalize + cast to bf16. One block per row.
__global__ __launch_bounds__(256) void normalize_kernel(
    const float* __restrict__ embs, unsigned short* __restrict__ xb) {
  const int row = blockIdx.x;
  const int t = threadIdx.x;
  const float4 v = ((const float4*)(embs + (size_t)row * DD))[t];
  float ss = v.x * v.x + v.y * v.y + v.z * v.z + v.w * v.w;
#pragma unroll
  for (int off = 32; off > 0; off >>= 1) ss += __shfl_down(ss, off, 64);
  __shared__ float red[4];
  const int w = t >> 6, lane = t & 63;
  if (lane == 0) red[w] = ss;
  __syncthreads();
  const float tot = red[0] + red[1] + red[2] + red[3];
  const float rn = 1.0f / fmaxf(sqrtf(tot), 1e-8f);
  ushort4 o;
  o.x = f2bf(v.x * rn);
  o.y = f2bf(v.y * rn);
  o.z = f2bf(v.z * rn);
  o.w = f2bf(v.w * rn);
  ((ushort4*)(xb + (size_t)row * DD))[t] = o;
}

// Kernel 2: fused sim-GEMM + per-row {sum exp, sum lbl*s, sum lbl}.
// 128x128 tile, BK=64, 256 threads = 4 waves in 2x2 (each wave 64x64 via
// 4x4 grid of 16x16x32 bf16 MFMAs). Grid = 64 i-blocks x 8 j-chunks(1024).
__global__ __launch_bounds__(256) void simloss_kernel(
    const unsigned short* __restrict__ xb, const float* __restrict__ labels,
    float* __restrict__ accL, float* __restrict__ accS1,
    float* __restrict__ accS2) {
  __shared__ __align__(16) unsigned short As[128 * 64];
  __shared__ __align__(16) unsigned short Bs[128 * 64];

  const int iblk = blockIdx.x >> 3;   // 0..63
  const int chunk = blockIdx.x & 7;   // 0..7 (XCD-friendly: b, b+8 share chunk)
  const int i0 = iblk * 128;
  const int jbase = chunk * 1024;

  const int tid = threadIdx.x;
  const int w = tid >> 6;
  const int lane = tid & 63;
  const int quad = lane >> 4;
  const int l15 = lane & 15;
  const int wr = (w >> 1) * 64;  // wave row offset in 128-tile
  const int wc = (w & 1) * 64;   // wave col offset

  // staging: each wave moves 4 chunks of 8 rows x 64 k-elems (1KB each)
  const int schunk = w * 4;
  const int srow = lane >> 3;       // 0..7
  const int scol = (lane & 7) * 8;  // k element offset

  // per-lane row accumulators: row = wr + (ridx>>2)*16 + quad*4 + (ridx&3)
  float aLl[16], aS1[16], aS2[16];
#pragma unroll
  for (int i = 0; i < 16; ++i) { aLl[i] = 0.f; aS1[i] = 0.f; aS2[i] = 0.f; }

  for (int jt = 0; jt < 8; ++jt) {
    const int j0 = jbase + jt * 128;
    floatx4 acc[4][4];
#pragma unroll
    for (int a = 0; a < 4; ++a)
#pragma unroll
      for (int b = 0; b < 4; ++b) acc[a][b] = (floatx4){0.f, 0.f, 0.f, 0.f};

    for (int kt = 0; kt < 16; ++kt) {
      const int k0 = kt * 64;
#pragma unroll
      for (int it = 0; it < 4; ++it) {
        const int ch = schunk + it;
        const unsigned short* gA =
            xb + (size_t)(i0 + ch * 8 + srow) * DD + k0 + scol;
        load_lds16(gA, As + ch * 512);
        const unsigned short* gB =
            xb + (size_t)(j0 + ch * 8 + srow) * DD + k0 + scol;
        load_lds16(gB, Bs + ch * 512);
      }
      __syncthreads();  // drains vmcnt for global_load_lds

      bf16x8 af[4][2], bfr[4][2];
#pragma unroll
      for (int kf = 0; kf < 2; ++kf) {
#pragma unroll
        for (int rf = 0; rf < 4; ++rf)
          af[rf][kf] =
              *(const bf16x8*)(As + (wr + rf * 16 + l15) * 64 + kf * 32 + quad * 8);
#pragma unroll
        for (int cf = 0; cf < 4; ++cf)
          bfr[cf][kf] =
              *(const bf16x8*)(Bs + (wc + cf * 16 + l15) * 64 + kf * 32 + quad * 8);
      }
#pragma unroll
      for (int kf = 0; kf < 2; ++kf)
#pragma unroll
        for (int rf = 0; rf < 4; ++rf)
#pragma unroll
          for (int cf = 0; cf < 4; ++cf)
            acc[rf][cf] = __builtin_amdgcn_mfma_f32_16x16x32_bf16(
                af[rf][kf], bfr[cf][kf], acc[rf][cf], 0, 0, 0);
      __syncthreads();  // before next staging overwrites LDS
    }

    // epilogue: C/D layout col = lane&15, row = quad*4 + reg (m89/m91)
#pragma unroll
    for (int rf = 0; rf < 4; ++rf) {
#pragma unroll
      for (int reg = 0; reg < 4; ++reg) {
        const int row_g = i0 + wr + rf * 16 + quad * 4 + reg;
        const float* lp = labels + (size_t)row_g * NN + j0 + wc + l15;
        const int ridx = rf * 4 + reg;
#pragma unroll
        for (int cf = 0; cf < 4; ++cf) {
          const int col_g = j0 + wc + cf * 16 + l15;
          const float s = acc[rf][cf][reg] * 5.0f;  // /TEMPERATURE
          const float lbl = lp[cf * 16];
          const bool diag = (row_g == col_g);
          const float e = diag ? 0.f : __expf(s);
          const float lb = diag ? 0.f : lbl;
          aLl[ridx] += e;
          aS1[ridx] += lb * s;
          aS2[ridx] += lb;
        }
      }
    }
  }

  // reduce the 16 lanes (same quad) sharing each row, then 3 atomics/row
#pragma unroll
  for (int idx = 0; idx < 16; ++idx) {
    float vL = aLl[idx], v1 = aS1[idx], v2 = aS2[idx];
#pragma unroll
    for (int off = 1; off < 16; off <<= 1) {
      vL += __shfl_xor(vL, off, 64);
      v1 += __shfl_xor(v1, off, 64);
      v2 += __shfl_xor(v2, off, 64);
    }
    if (l15 == 0) {
      const int row_g = i0 + wr + (idx >> 2) * 16 + quad * 4 + (idx & 3);
      atomicAdd(&accL[row_g], vL);
      atomicAdd(&accS1[row_g], v1);
      atomicAdd(&accS2[row_g], v2);
    }
  }
}

// Kernel 3: loss = mean_i( S2_i*log(l_i) - S1_i )
__global__ __launch_bounds__(256) void finalize_kernel(
    const float* __restrict__ accL, const float* __restrict__ accS1,
    const float* __restrict__ accS2, float* __restrict__ out) {
  const int t = threadIdx.x;
  float sum = 0.f;
  for (int i = t; i < NN; i += 256)
    sum += accS2[i] * logf(accL[i]) - accS1[i];
#pragma unroll
  for (int off = 32; off > 0; off >>= 1) sum += __shfl_down(sum, off, 64);
  __shared__ float red[4];
  const int w = t >> 6, lane = t & 63;
  if (lane == 0) red[w] = sum;
  __syncthreads();
  if (t == 0) out[0] = (red[0] + red[1] + red[2] + red[3]) / (float)NN;
}

extern "C" void kernel_launch(void* const* d_in, const int* in_sizes, int n_in,
                              void* d_out, int out_size, void* d_ws,
                              size_t ws_size, hipStream_t stream) {
  const float* embs = (const float*)d_in[0];    // (8192,1024) fp32
  const float* labels = (const float*)d_in[1];  // (8192,8192) fp32
  float* out = (float*)d_out;

  // workspace: [0,16MB) bf16 normalized X; then 3 x 8192 fp32 row accums
  unsigned short* xb = (unsigned short*)d_ws;
  float* accL = (float*)((char*)d_ws + (size_t)NN * DD * 2);
  float* accS1 = accL + NN;
  float* accS2 = accS1 + NN;

  hipMemsetAsync(accL, 0, 3 * NN * sizeof(float), stream);
  normalize_kernel<<<NN, 256, 0, stream>>>(embs, xb);
  simloss_kernel<<<512, 256, 0, stream>>>(xb, labels, accL, accS1, accS2);
  finalize_kernel<<<1, 256, 0, stream>>>(accL, accS1, accS2, out);
}

// Round 2
// 657.357 us; speedup vs baseline: 1.0352x; 1.0352x over previous
//
#include <hip/hip_runtime.h>
#include <hip/hip_bf16.h>

// Problem constants (reference: n=8192, d=1024, T=0.2, eps=1e-8)
#define NN 8192
#define DD 1024

typedef __attribute__((ext_vector_type(8))) short bf16x8;   // 8 bf16 = 4 VGPRs
typedef __attribute__((ext_vector_type(4))) float floatx4;  // MFMA C/D frag

__device__ __forceinline__ void load_lds16(const void* g, void* l) {
  // async global->LDS, 16B per lane; LDS dest = wave-uniform base + lane*16
  __builtin_amdgcn_global_load_lds(
      (const __attribute__((address_space(1))) unsigned int*)g,
      (__attribute__((address_space(3))) unsigned int*)l, 16, 0, 0);
}

__device__ __forceinline__ unsigned short f2bf(float x) {
  // round-to-nearest-even fp32 -> bf16
  unsigned int u = __float_as_uint(x);
  u = (u + 0x7fffu + ((u >> 16) & 1u)) >> 16;
  return (unsigned short)u;
}

// Kernel 1: row L2-normalize + cast to bf16. One block per row.
__global__ __launch_bounds__(256) void normalize_kernel(
    const float* __restrict__ embs, unsigned short* __restrict__ xb) {
  const int row = blockIdx.x;
  const int t = threadIdx.x;
  const float4 v = ((const float4*)(embs + (size_t)row * DD))[t];
  float ss = v.x * v.x + v.y * v.y + v.z * v.z + v.w * v.w;
#pragma unroll
  for (int off = 32; off > 0; off >>= 1) ss += __shfl_down(ss, off, 64);
  __shared__ float red[4];
  const int w = t >> 6, lane = t & 63;
  if (lane == 0) red[w] = ss;
  __syncthreads();
  const float tot = red[0] + red[1] + red[2] + red[3];
  const float rn = 1.0f / fmaxf(sqrtf(tot), 1e-8f);
  ushort4 o;
  o.x = f2bf(v.x * rn);
  o.y = f2bf(v.y * rn);
  o.z = f2bf(v.z * rn);
  o.w = f2bf(v.w * rn);
  ((ushort4*)(xb + (size_t)row * DD))[t] = o;
}

// Kernel 2: fused sim-GEMM + per-row {sum exp, sum lbl*s, sum lbl}.
// 128x128 tile, BK=64, 256 threads = 4 waves in 2x2 (each wave 64x64 via
// 4x4 grid of 16x16x32 bf16 MFMAs).
// Grid = 64 i-blocks x 16 j-chunks (512 cols each -> 4 j-tiles per block).
// LDS layout is XOR-swizzled: the 16B k-group stored at physical slot p of
// row r holds logical k-group g = p ^ (r&7). global_load_lds forces
// dest = base + lane*16, so the swizzle is applied on the global SOURCE
// address at staging time and undone at ds_read time. This spreads each
// quarter-wave's ds_read_b128 across all 32 banks (was: 16-way conflict
// from the 128B row stride -> SQ_LDS_BANK_CONFLICT 5e7).
__global__ __launch_bounds__(256) void simloss_kernel(
    const unsigned short* __restrict__ xb, const float* __restrict__ labels,
    float* __restrict__ accL, float* __restrict__ accS1,
    float* __restrict__ accS2) {
  __shared__ __align__(16) unsigned short As[128 * 64];
  __shared__ __align__(16) unsigned short Bs[128 * 64];

  const int iblk = blockIdx.x >> 4;    // 0..63
  const int chunk = blockIdx.x & 15;   // 0..15
  const int i0 = iblk * 128;
  const int jbase = chunk * 512;

  const int tid = threadIdx.x;
  const int w = tid >> 6;
  const int lane = tid & 63;
  const int quad = lane >> 4;
  const int l15 = lane & 15;
  const int wr = (w >> 1) * 64;  // wave row offset in 128-tile
  const int wc = (w & 1) * 64;   // wave col offset

  // staging: each wave moves 4 chunks of 8 rows x 64 k-elems (1KB each)
  const int schunk = w * 4;
  const int srow = lane >> 3;                      // 0..7 row within chunk
  const int scol = ((lane & 7) ^ srow) * 8;        // swizzled k source group

  // per-lane row accumulators: row = wr + (ridx>>2)*16 + quad*4 + (ridx&3)
  float aLl[16], aS1[16], aS2[16];
#pragma unroll
  for (int i = 0; i < 16; ++i) { aLl[i] = 0.f; aS1[i] = 0.f; aS2[i] = 0.f; }

  for (int jt = 0; jt < 4; ++jt) {
    const int j0 = jbase + jt * 128;
    floatx4 acc[4][4];
#pragma unroll
    for (int a = 0; a < 4; ++a)
#pragma unroll
      for (int b = 0; b < 4; ++b) acc[a][b] = (floatx4){0.f, 0.f, 0.f, 0.f};

    for (int kt = 0; kt < 16; ++kt) {
      const int k0 = kt * 64;
#pragma unroll
      for (int it = 0; it < 4; ++it) {
        const int ch = schunk + it;
        const unsigned short* gA =
            xb + (size_t)(i0 + ch * 8 + srow) * DD + k0 + scol;
        load_lds16(gA, As + ch * 512);
        const unsigned short* gB =
            xb + (size_t)(j0 + ch * 8 + srow) * DD + k0 + scol;
        load_lds16(gB, Bs + ch * 512);
      }
      __syncthreads();  // drains vmcnt for global_load_lds

      // kf split: only 8 fragments (32 VGPR) live at a time (VGPR pressure)
#pragma unroll
      for (int kf = 0; kf < 2; ++kf) {
        bf16x8 af[4], bfr[4];
        const int pg = ((kf * 4 + quad) ^ (l15 & 7)) * 8;  // swizzled read
#pragma unroll
        for (int rf = 0; rf < 4; ++rf)
          af[rf] = *(const bf16x8*)(As + (wr + rf * 16 + l15) * 64 + pg);
#pragma unroll
        for (int cf = 0; cf < 4; ++cf)
          bfr[cf] = *(const bf16x8*)(Bs + (wc + cf * 16 + l15) * 64 + pg);
#pragma unroll
        for (int rf = 0; rf < 4; ++rf)
#pragma unroll
          for (int cf = 0; cf < 4; ++cf)
            acc[rf][cf] = __builtin_amdgcn_mfma_f32_16x16x32_bf16(
                af[rf], bfr[cf], acc[rf][cf], 0, 0, 0);
      }
      __syncthreads();  // before next staging overwrites LDS
    }

    // epilogue: C/D layout col = lane&15, row = quad*4 + reg (m89/m91)
#pragma unroll
    for (int rf = 0; rf < 4; ++rf) {
#pragma unroll
      for (int reg = 0; reg < 4; ++reg) {
        const int row_g = i0 + wr + rf * 16 + quad * 4 + reg;
        const float* lp = labels + (size_t)row_g * NN + j0 + wc + l15;
        const int ridx = rf * 4 + reg;
#pragma unroll
        for (int cf = 0; cf < 4; ++cf) {
          const int col_g = j0 + wc + cf * 16 + l15;
          const float s = acc[rf][cf][reg] * 5.0f;  // /TEMPERATURE
          const float lbl = lp[cf * 16];
          const bool diag = (row_g == col_g);
          const float e = diag ? 0.f : __expf(s);
          const float lb = diag ? 0.f : lbl;
          aLl[ridx] += e;
          aS1[ridx] += lb * s;
          aS2[ridx] += lb;
        }
      }
    }
  }

  // reduce the 16 lanes (same quad) sharing each row, then 3 atomics/row
#pragma unroll
  for (int idx = 0; idx < 16; ++idx) {
    float vL = aLl[idx], v1 = aS1[idx], v2 = aS2[idx];
#pragma unroll
    for (int off = 1; off < 16; off <<= 1) {
      vL += __shfl_xor(vL, off, 64);
      v1 += __shfl_xor(v1, off, 64);
      v2 += __shfl_xor(v2, off, 64);
    }
    if (l15 == 0) {
      const int row_g = i0 + wr + (idx >> 2) * 16 + quad * 4 + (idx & 3);
      atomicAdd(&accL[row_g], vL);
      atomicAdd(&accS1[row_g], v1);
      atomicAdd(&accS2[row_g], v2);
    }
  }
}

// Kernel 3: loss = mean_i( S2_i*log(l_i) - S1_i )
__global__ __launch_bounds__(256) void finalize_kernel(
    const float* __restrict__ accL, const float* __restrict__ accS1,
    const float* __restrict__ accS2, float* __restrict__ out) {
  const int t = threadIdx.x;
  float sum = 0.f;
  for (int i = t; i < NN; i += 256)
    sum += accS2[i] * logf(accL[i]) - accS1[i];
#pragma unroll
  for (int off = 32; off > 0; off >>= 1) sum += __shfl_down(sum, off, 64);
  __shared__ float red[4];
  const int w = t >> 6, lane = t & 63;
  if (lane == 0) red[w] = sum;
  __syncthreads();
  if (t == 0) out[0] = (red[0] + red[1] + red[2] + red[3]) / (float)NN;
}

extern "C" void kernel_launch(void* const* d_in, const int* in_sizes, int n_in,
                              void* d_out, int out_size, void* d_ws,
                              size_t ws_size, hipStream_t stream) {
  const float* embs = (const float*)d_in[0];    // (8192,1024) fp32
  const float* labels = (const float*)d_in[1];  // (8192,8192) fp32
  float* out = (float*)d_out;

  // workspace: [0,16MB) bf16 normalized X; then 3 x 8192 fp32 row accums
  unsigned short* xb = (unsigned short*)d_ws;
  float* accL = (float*)((char*)d_ws + (size_t)NN * DD * 2);
  float* accS1 = accL + NN;
  float* accS2 = accS1 + NN;

  hipMemsetAsync(accL, 0, 3 * NN * sizeof(float), stream);
  normalize_kernel<<<NN, 256, 0, stream>>>(embs, xb);
  simloss_kernel<<<1024, 256, 0, stream>>>(xb, labels, accL, accS1, accS2);
  finalize_kernel<<<1, 256, 0, stream>>>(accL, accS1, accS2, out);
}

// Round 3
// 630.923 us; speedup vs baseline: 1.0786x; 1.0419x over previous
//
#include <hip/hip_runtime.h>
#include <hip/hip_bf16.h>

// Problem constants (reference: n=8192, d=1024, T=0.2, eps=1e-8)
#define NN 8192
#define DD 1024

typedef __attribute__((ext_vector_type(8))) short bf16x8;   // 8 bf16 = 4 VGPRs
typedef __attribute__((ext_vector_type(4))) float floatx4;  // MFMA C/D frag

__device__ __forceinline__ void load_lds16(const void* g, void* l) {
  // async global->LDS, 16B per lane; LDS dest = wave-uniform base + lane*16
  __builtin_amdgcn_global_load_lds(
      (const __attribute__((address_space(1))) unsigned int*)g,
      (__attribute__((address_space(3))) unsigned int*)l, 16, 0, 0);
}

__device__ __forceinline__ unsigned short f2bf(float x) {
  // round-to-nearest-even fp32 -> bf16
  unsigned int u = __float_as_uint(x);
  u = (u + 0x7fffu + ((u >> 16) & 1u)) >> 16;
  return (unsigned short)u;
}

// Kernel 1: row L2-normalize + cast to bf16. One block per row.
// Also zero-inits the 3 per-row accumulators (replaces a memset dispatch).
__global__ __launch_bounds__(256) void normalize_kernel(
    const float* __restrict__ embs, unsigned short* __restrict__ xb,
    float* __restrict__ accL, float* __restrict__ accS1,
    float* __restrict__ accS2) {
  const int row = blockIdx.x;
  const int t = threadIdx.x;
  if (t == 0) { accL[row] = 0.f; accS1[row] = 0.f; accS2[row] = 0.f; }
  const float4 v = ((const float4*)(embs + (size_t)row * DD))[t];
  float ss = v.x * v.x + v.y * v.y + v.z * v.z + v.w * v.w;
#pragma unroll
  for (int off = 32; off > 0; off >>= 1) ss += __shfl_down(ss, off, 64);
  __shared__ float red[4];
  const int w = t >> 6, lane = t & 63;
  if (lane == 0) red[w] = ss;
  __syncthreads();
  const float tot = red[0] + red[1] + red[2] + red[3];
  const float rn = 1.0f / fmaxf(sqrtf(tot), 1e-8f);
  ushort4 o;
  o.x = f2bf(v.x * rn);
  o.y = f2bf(v.y * rn);
  o.z = f2bf(v.z * rn);
  o.w = f2bf(v.w * rn);
  ((ushort4*)(xb + (size_t)row * DD))[t] = o;
}

// Kernel 2: fused sim-GEMM + per-row {sum exp, sum lbl*s, sum lbl}.
// SYMMETRY: sim is symmetric, so only upper-triangular 128x128 tiles are
// computed (2080 of 4096). Off-diag tile (bi<bj) contributes to rows i
// (reduce across l15) AND rows j (transpose side: in-lane sum over rf/reg
// + quad shuffles); exp(s) computed once serves both sides. Diagonal tiles
// use the masked i-side epilogue only.
// 128x128 tile, BK=64, 256 threads = 4 waves in 2x2 (each wave 64x64 via
// 4x4 grid of 16x16x32 bf16 MFMAs).
// LDS XOR-swizzle (R2): physical 16B-group p of row r holds logical group
// p ^ (r&7); applied on the global source at staging, undone at ds_read.
__global__ __launch_bounds__(256) void simloss_kernel(
    const unsigned short* __restrict__ xb, const float* __restrict__ labels,
    float* __restrict__ accL, float* __restrict__ accS1,
    float* __restrict__ accS2) {
  __shared__ __align__(16) unsigned short As[128 * 64];
  __shared__ __align__(16) unsigned short Bs[128 * 64];

  // triangular decode: t -> (bi, bj), bi <= bj, row-major over bj
  const int t = blockIdx.x;
  int bi = (int)((129.0 - sqrt(129.0 * 129.0 - 8.0 * (double)t)) * 0.5);
  while (64 * (bi + 1) - ((bi + 1) * bi) / 2 <= t) ++bi;
  while (64 * bi - (bi * (bi - 1)) / 2 > t) --bi;
  const int bj = bi + (t - (64 * bi - (bi * (bi - 1)) / 2));
  const bool diag = (bi == bj);
  const int i0 = bi * 128;
  const int j0 = bj * 128;

  const int tid = threadIdx.x;
  const int w = tid >> 6;
  const int lane = tid & 63;
  const int quad = lane >> 4;
  const int l15 = lane & 15;
  const int wr = (w >> 1) * 64;  // wave row offset in 128-tile
  const int wc = (w & 1) * 64;   // wave col offset

  // staging: each wave moves 4 chunks of 8 rows x 64 k-elems (1KB each)
  const int schunk = w * 4;
  const int srow = lane >> 3;                // 0..7 row within chunk
  const int scol = ((lane & 7) ^ srow) * 8;  // swizzled k source group

  floatx4 acc[4][4];
#pragma unroll
  for (int a = 0; a < 4; ++a)
#pragma unroll
    for (int b = 0; b < 4; ++b) acc[a][b] = (floatx4){0.f, 0.f, 0.f, 0.f};

  for (int kt = 0; kt < 16; ++kt) {
    const int k0 = kt * 64;
#pragma unroll
    for (int it = 0; it < 4; ++it) {
      const int ch = schunk + it;
      const unsigned short* gA =
          xb + (size_t)(i0 + ch * 8 + srow) * DD + k0 + scol;
      load_lds16(gA, As + ch * 512);
      const unsigned short* gB =
          xb + (size_t)(j0 + ch * 8 + srow) * DD + k0 + scol;
      load_lds16(gB, Bs + ch * 512);
    }
    __syncthreads();  // drains vmcnt for global_load_lds

#pragma unroll
    for (int kf = 0; kf < 2; ++kf) {
      bf16x8 af[4], bfr[4];
      const int pg = ((kf * 4 + quad) ^ (l15 & 7)) * 8;  // swizzled read
#pragma unroll
      for (int rf = 0; rf < 4; ++rf)
        af[rf] = *(const bf16x8*)(As + (wr + rf * 16 + l15) * 64 + pg);
#pragma unroll
      for (int cf = 0; cf < 4; ++cf)
        bfr[cf] = *(const bf16x8*)(Bs + (wc + cf * 16 + l15) * 64 + pg);
#pragma unroll
      for (int rf = 0; rf < 4; ++rf)
#pragma unroll
        for (int cf = 0; cf < 4; ++cf)
          acc[rf][cf] = __builtin_amdgcn_mfma_f32_16x16x32_bf16(
              af[rf], bfr[cf], acc[rf][cf], 0, 0, 0);
    }
    __syncthreads();  // before next staging overwrites LDS
  }

  // Epilogue. C/D layout: col = l15, row = quad*4 + reg (m89/m91).
  if (!diag) {
    float bL[4], bS1[4], bS2[4];  // j-side (transpose) accum, per cf
#pragma unroll
    for (int cf = 0; cf < 4; ++cf) { bL[cf] = 0.f; bS1[cf] = 0.f; bS2[cf] = 0.f; }

#pragma unroll
    for (int rf = 0; rf < 4; ++rf) {
      // transposed labels labels[c_g][r_g]: one float4 per cf covers reg 0..3
      float4 tl[4];
#pragma unroll
      for (int cf = 0; cf < 4; ++cf)
        tl[cf] = *(const float4*)(labels +
                                  (size_t)(j0 + wc + cf * 16 + l15) * NN +
                                  i0 + wr + rf * 16 + quad * 4);
#pragma unroll
      for (int reg = 0; reg < 4; ++reg) {
        const int row_g = i0 + wr + rf * 16 + quad * 4 + reg;
        const float* lp = labels + (size_t)row_g * NN + j0 + wc + l15;
        float vL = 0.f, v1 = 0.f, v2 = 0.f;
#pragma unroll
        for (int cf = 0; cf < 4; ++cf) {
          const float s = acc[rf][cf][reg] * 5.0f;  // /TEMPERATURE
          const float e = __expf(s);
          const float lbl = lp[cf * 16];
          vL += e;
          v1 += lbl * s;
          v2 += lbl;
          const float tlbl = (reg == 0)   ? tl[cf].x
                             : (reg == 1) ? tl[cf].y
                             : (reg == 2) ? tl[cf].z
                                          : tl[cf].w;
          bL[cf] += e;
          bS1[cf] += tlbl * s;
          bS2[cf] += tlbl;
        }
        // 16 lanes (same quad) share row_g
#pragma unroll
        for (int off = 1; off < 16; off <<= 1) {
          vL += __shfl_xor(vL, off, 64);
          v1 += __shfl_xor(v1, off, 64);
          v2 += __shfl_xor(v2, off, 64);
        }
        if (l15 == 0) {
          atomicAdd(&accL[row_g], vL);
          atomicAdd(&accS1[row_g], v1);
          atomicAdd(&accS2[row_g], v2);
        }
      }
    }
    // j-side: sum across the 4 quads (lanes quad*16+l15 share column c_g)
#pragma unroll
    for (int cf = 0; cf < 4; ++cf) {
      float vL = bL[cf], v1 = bS1[cf], v2 = bS2[cf];
      vL += __shfl_xor(vL, 16, 64);
      v1 += __shfl_xor(v1, 16, 64);
      v2 += __shfl_xor(v2, 16, 64);
      vL += __shfl_xor(vL, 32, 64);
      v1 += __shfl_xor(v1, 32, 64);
      v2 += __shfl_xor(v2, 32, 64);
      if (quad == 0) {
        const int c_g = j0 + wc + cf * 16 + l15;
        atomicAdd(&accL[c_g], vL);
        atomicAdd(&accS1[c_g], v1);
        atomicAdd(&accS2[c_g], v2);
      }
    }
  } else {
    // diagonal tile: i-side only, diag-masked
#pragma unroll
    for (int rf = 0; rf < 4; ++rf) {
#pragma unroll
      for (int reg = 0; reg < 4; ++reg) {
        const int row_g = i0 + wr + rf * 16 + quad * 4 + reg;
        const float* lp = labels + (size_t)row_g * NN + j0 + wc + l15;
        float vL = 0.f, v1 = 0.f, v2 = 0.f;
#pragma unroll
        for (int cf = 0; cf < 4; ++cf) {
          const int col_g = j0 + wc + cf * 16 + l15;
          const float s = acc[rf][cf][reg] * 5.0f;
          const bool d = (row_g == col_g);
          const float e = d ? 0.f : __expf(s);
          const float lbl = d ? 0.f : lp[cf * 16];
          vL += e;
          v1 += lbl * s;
          v2 += lbl;
        }
#pragma unroll
        for (int off = 1; off < 16; off <<= 1) {
          vL += __shfl_xor(vL, off, 64);
          v1 += __shfl_xor(v1, off, 64);
          v2 += __shfl_xor(v2, off, 64);
        }
        if (l15 == 0) {
          atomicAdd(&accL[row_g], vL);
          atomicAdd(&accS1[row_g], v1);
          atomicAdd(&accS2[row_g], v2);
        }
      }
    }
  }
}

// Kernel 3: loss = mean_i( S2_i*log(l_i) - S1_i )
__global__ __launch_bounds__(256) void finalize_kernel(
    const float* __restrict__ accL, const float* __restrict__ accS1,
    const float* __restrict__ accS2, float* __restrict__ out) {
  const int t = threadIdx.x;
  float sum = 0.f;
  for (int i = t; i < NN; i += 256)
    sum += accS2[i] * logf(accL[i]) - accS1[i];
#pragma unroll
  for (int off = 32; off > 0; off >>= 1) sum += __shfl_down(sum, off, 64);
  __shared__ float red[4];
  const int w = t >> 6, lane = t & 63;
  if (lane == 0) red[w] = sum;
  __syncthreads();
  if (t == 0) out[0] = (red[0] + red[1] + red[2] + red[3]) / (float)NN;
}

extern "C" void kernel_launch(void* const* d_in, const int* in_sizes, int n_in,
                              void* d_out, int out_size, void* d_ws,
                              size_t ws_size, hipStream_t stream) {
  const float* embs = (const float*)d_in[0];    // (8192,1024) fp32
  const float* labels = (const float*)d_in[1];  // (8192,8192) fp32
  float* out = (float*)d_out;

  // workspace: [0,16MB) bf16 normalized X; then 3 x 8192 fp32 row accums
  unsigned short* xb = (unsigned short*)d_ws;
  float* accL = (float*)((char*)d_ws + (size_t)NN * DD * 2);
  float* accS1 = accL + NN;
  float* accS2 = accS1 + NN;

  normalize_kernel<<<NN, 256, 0, stream>>>(embs, xb, accL, accS1, accS2);
  simloss_kernel<<<2080, 256, 0, stream>>>(xb, labels, accL, accS1, accS2);
  finalize_kernel<<<1, 256, 0, stream>>>(accL, accS1, accS2, out);
}

// Round 4
// 547.646 us; speedup vs baseline: 1.2426x; 1.1521x over previous
//
#include <hip/hip_runtime.h>
#include <hip/hip_bf16.h>

// Problem constants (reference: n=8192, d=1024, T=0.2, eps=1e-8)
#define NN 8192
#define DD 1024
#define NTILE 64            // 8192/128 tile blocks per dim
#define NUT (64 * 65 / 2)   // 2080 upper-tri tiles

typedef __attribute__((ext_vector_type(8))) short bf16x8;   // 8 bf16 = 4 VGPRs
typedef __attribute__((ext_vector_type(4))) float floatx4;  // MFMA C/D frag
typedef __attribute__((ext_vector_type(8))) _Float16 h16x8; // 16B of fp16

__device__ __forceinline__ void load_lds16(const void* g, void* l) {
  // async global->LDS, 16B per lane; LDS dest = wave-uniform base + lane*16
  __builtin_amdgcn_global_load_lds(
      (const __attribute__((address_space(1))) unsigned int*)g,
      (__attribute__((address_space(3))) unsigned int*)l, 16, 0, 0);
}

__device__ __forceinline__ unsigned short f2bf(float x) {
  // round-to-nearest-even fp32 -> bf16
  unsigned int u = __float_as_uint(x);
  u = (u + 0x7fffu + ((u >> 16) & 1u)) >> 16;
  return (unsigned short)u;
}

// triangular decode: t -> (bi, bj), bi <= bj, row-major over bj
__device__ __forceinline__ void tri_decode(int t, int& bi, int& bj) {
  bi = (int)((129.0 - sqrt(129.0 * 129.0 - 8.0 * (double)t)) * 0.5);
  while (NTILE * (bi + 1) - ((bi + 1) * bi) / 2 <= t) ++bi;
  while (NTILE * bi - (bi * (bi - 1)) / 2 > t) --bi;
  bj = bi + (t - (NTILE * bi - (bi * (bi - 1)) / 2));
}

// Kernel 1: row L2-normalize + cast to bf16. One block per row.
// Also zero-inits the 3 per-row accumulators (replaces a memset dispatch).
__global__ __launch_bounds__(256) void normalize_kernel(
    const float* __restrict__ embs, unsigned short* __restrict__ xb,
    float* __restrict__ accL, float* __restrict__ accS1,
    float* __restrict__ accS2) {
  const int row = blockIdx.x;
  const int t = threadIdx.x;
  if (t == 0) { accL[row] = 0.f; accS1[row] = 0.f; accS2[row] = 0.f; }
  const float4 v = ((const float4*)(embs + (size_t)row * DD))[t];
  float ss = v.x * v.x + v.y * v.y + v.z * v.z + v.w * v.w;
#pragma unroll
  for (int off = 32; off > 0; off >>= 1) ss += __shfl_down(ss, off, 64);
  __shared__ float red[4];
  const int w = t >> 6, lane = t & 63;
  if (lane == 0) red[w] = ss;
  __syncthreads();
  const float tot = red[0] + red[1] + red[2] + red[3];
  const float rn = 1.0f / fmaxf(sqrtf(tot), 1e-8f);
  ushort4 o;
  o.x = f2bf(v.x * rn);
  o.y = f2bf(v.y * rn);
  o.z = f2bf(v.z * rn);
  o.w = f2bf(v.w * rn);
  ((ushort4*)(xb + (size_t)row * DD))[t] = o;
}

// Phase A: pure GEMM over upper-triangular 128x128 tiles; writes scaled
// scores s = sim*5 as fp16 into the packed tile buffer (tile b at
// simb + b*16384, row-major 128x128). No epilogue math, no atomics -> the
// m97-proven structure. LDS XOR-swizzle: physical 16B-group p of row r
// holds logical group p ^ (r&7) (0 bank conflicts, verified R2).
__global__ __launch_bounds__(256) void gemm_kernel(
    const unsigned short* __restrict__ xb, _Float16* __restrict__ simb) {
  __shared__ __align__(16) unsigned short As[128 * 64];
  __shared__ __align__(16) unsigned short Bs[128 * 64];

  int bi, bj;
  tri_decode(blockIdx.x, bi, bj);
  const int i0 = bi * 128;
  const int j0 = bj * 128;

  const int tid = threadIdx.x;
  const int w = tid >> 6;
  const int lane = tid & 63;
  const int quad = lane >> 4;
  const int l15 = lane & 15;
  const int wr = (w >> 1) * 64;
  const int wc = (w & 1) * 64;

  const int schunk = w * 4;
  const int srow = lane >> 3;
  const int scol = ((lane & 7) ^ srow) * 8;

  floatx4 acc[4][4];
#pragma unroll
  for (int a = 0; a < 4; ++a)
#pragma unroll
    for (int b = 0; b < 4; ++b) acc[a][b] = (floatx4){0.f, 0.f, 0.f, 0.f};

  for (int kt = 0; kt < 16; ++kt) {
    const int k0 = kt * 64;
#pragma unroll
    for (int it = 0; it < 4; ++it) {
      const int ch = schunk + it;
      const unsigned short* gA =
          xb + (size_t)(i0 + ch * 8 + srow) * DD + k0 + scol;
      load_lds16(gA, As + ch * 512);
      const unsigned short* gB =
          xb + (size_t)(j0 + ch * 8 + srow) * DD + k0 + scol;
      load_lds16(gB, Bs + ch * 512);
    }
    __syncthreads();

#pragma unroll
    for (int kf = 0; kf < 2; ++kf) {
      bf16x8 af[4], bfr[4];
      const int pg = ((kf * 4 + quad) ^ (l15 & 7)) * 8;
#pragma unroll
      for (int rf = 0; rf < 4; ++rf)
        af[rf] = *(const bf16x8*)(As + (wr + rf * 16 + l15) * 64 + pg);
#pragma unroll
      for (int cf = 0; cf < 4; ++cf)
        bfr[cf] = *(const bf16x8*)(Bs + (wc + cf * 16 + l15) * 64 + pg);
#pragma unroll
      for (int rf = 0; rf < 4; ++rf)
#pragma unroll
        for (int cf = 0; cf < 4; ++cf)
          acc[rf][cf] = __builtin_amdgcn_mfma_f32_16x16x32_bf16(
              af[rf], bfr[cf], acc[rf][cf], 0, 0, 0);
    }
    __syncthreads();
  }

  // store: C/D layout col = l15, row = quad*4 + reg (m89/m91); scale by 5
  _Float16* tile = simb + (size_t)blockIdx.x * (128 * 128);
#pragma unroll
  for (int rf = 0; rf < 4; ++rf)
#pragma unroll
    for (int cf = 0; cf < 4; ++cf) {
      const int col = wc + cf * 16 + l15;
#pragma unroll
      for (int reg = 0; reg < 4; ++reg) {
        const int row = wr + rf * 16 + quad * 4 + reg;
        tile[row * 128 + col] = (_Float16)(acc[rf][cf][reg] * 5.0f);
      }
    }
}

// Phase B: streaming reduce. One block per tile (same decode).
// pass 1 (i-side): thread t -> tile row r = t>>1, col half (t&1)*64..+63;
//   coalesced float4 label loads + 16B sim loads; pair-reduce via shfl.
// pass 2 (j-side, off-diag only): thread t -> tile col c = t>>1, row half;
//   sim read transposed (L2-hot 32KB tile), labels[j][i] coalesced.
__global__ __launch_bounds__(256) void reduce_kernel(
    const _Float16* __restrict__ simb, const float* __restrict__ labels,
    float* __restrict__ accL, float* __restrict__ accS1,
    float* __restrict__ accS2) {
  int bi, bj;
  tri_decode(blockIdx.x, bi, bj);
  const int i0 = bi * 128;
  const int j0 = bj * 128;
  const bool diag = (bi == bj);
  const _Float16* tile = simb + (size_t)blockIdx.x * (128 * 128);

  const int t = threadIdx.x;
  const int r = t >> 1;
  const int cbase = (t & 1) * 64;

  // ---- pass 1: rows ----
  {
    float vL = 0.f, v1 = 0.f, v2 = 0.f;
    const float* lrow = labels + (size_t)(i0 + r) * NN + j0 + cbase;
    const _Float16* srow = tile + r * 128 + cbase;
#pragma unroll 2
    for (int kk = 0; kk < 8; ++kk) {
      const h16x8 sv = ((const h16x8*)srow)[kk];
      const float4 l0 = ((const float4*)lrow)[2 * kk];
      const float4 l1 = ((const float4*)lrow)[2 * kk + 1];
      const float ls[8] = {l0.x, l0.y, l0.z, l0.w, l1.x, l1.y, l1.z, l1.w};
#pragma unroll
      for (int e = 0; e < 8; ++e) {
        const int c = cbase + kk * 8 + e;
        const float s = (float)sv[e];
        const bool d = diag && (c == r);
        const float ex = d ? 0.f : __expf(s);
        const float lb = d ? 0.f : ls[e];
        vL += ex;
        v1 += lb * s;
        v2 += lb;
      }
    }
    vL += __shfl_xor(vL, 1, 64);
    v1 += __shfl_xor(v1, 1, 64);
    v2 += __shfl_xor(v2, 1, 64);
    if ((t & 1) == 0) {
      atomicAdd(&accL[i0 + r], vL);
      atomicAdd(&accS1[i0 + r], v1);
      atomicAdd(&accS2[i0 + r], v2);
    }
  }

  // ---- pass 2: cols (off-diag tiles only) ----
  if (!diag) {
    const int c = t >> 1;
    const int rbase = (t & 1) * 64;
    float vL = 0.f, v1 = 0.f, v2 = 0.f;
    const float* lrow = labels + (size_t)(j0 + c) * NN + i0 + rbase;
#pragma unroll 2
    for (int kk = 0; kk < 16; ++kk) {
      const float4 lb4 = ((const float4*)lrow)[kk];
      const float ls[4] = {lb4.x, lb4.y, lb4.z, lb4.w};
#pragma unroll
      for (int e = 0; e < 4; ++e) {
        const int rr = rbase + kk * 4 + e;
        const float s = (float)tile[rr * 128 + c];
        vL += __expf(s);
        v1 += ls[e] * s;
        v2 += ls[e];
      }
    }
    vL += __shfl_xor(vL, 1, 64);
    v1 += __shfl_xor(v1, 1, 64);
    v2 += __shfl_xor(v2, 1, 64);
    if ((t & 1) == 0) {
      atomicAdd(&accL[j0 + c], vL);
      atomicAdd(&accS1[j0 + c], v1);
      atomicAdd(&accS2[j0 + c], v2);
    }
  }
}

// ---- R3 fused fallback (used only if ws_size too small for simb) ----
__global__ __launch_bounds__(256) void simloss_kernel(
    const unsigned short* __restrict__ xb, const float* __restrict__ labels,
    float* __restrict__ accL, float* __restrict__ accS1,
    float* __restrict__ accS2) {
  __shared__ __align__(16) unsigned short As[128 * 64];
  __shared__ __align__(16) unsigned short Bs[128 * 64];
  int bi, bj;
  tri_decode(blockIdx.x, bi, bj);
  const bool diag = (bi == bj);
  const int i0 = bi * 128, j0 = bj * 128;
  const int tid = threadIdx.x;
  const int w = tid >> 6, lane = tid & 63;
  const int quad = lane >> 4, l15 = lane & 15;
  const int wr = (w >> 1) * 64, wc = (w & 1) * 64;
  const int schunk = w * 4, srow = lane >> 3;
  const int scol = ((lane & 7) ^ srow) * 8;
  floatx4 acc[4][4];
#pragma unroll
  for (int a = 0; a < 4; ++a)
#pragma unroll
    for (int b = 0; b < 4; ++b) acc[a][b] = (floatx4){0.f, 0.f, 0.f, 0.f};
  for (int kt = 0; kt < 16; ++kt) {
    const int k0 = kt * 64;
#pragma unroll
    for (int it = 0; it < 4; ++it) {
      const int ch = schunk + it;
      load_lds16(xb + (size_t)(i0 + ch * 8 + srow) * DD + k0 + scol,
                 As + ch * 512);
      load_lds16(xb + (size_t)(j0 + ch * 8 + srow) * DD + k0 + scol,
                 Bs + ch * 512);
    }
    __syncthreads();
#pragma unroll
    for (int kf = 0; kf < 2; ++kf) {
      bf16x8 af[4], bfr[4];
      const int pg = ((kf * 4 + quad) ^ (l15 & 7)) * 8;
#pragma unroll
      for (int rf = 0; rf < 4; ++rf)
        af[rf] = *(const bf16x8*)(As + (wr + rf * 16 + l15) * 64 + pg);
#pragma unroll
      for (int cf = 0; cf < 4; ++cf)
        bfr[cf] = *(const bf16x8*)(Bs + (wc + cf * 16 + l15) * 64 + pg);
#pragma unroll
      for (int rf = 0; rf < 4; ++rf)
#pragma unroll
        for (int cf = 0; cf < 4; ++cf)
          acc[rf][cf] = __builtin_amdgcn_mfma_f32_16x16x32_bf16(
              af[rf], bfr[cf], acc[rf][cf], 0, 0, 0);
    }
    __syncthreads();
  }
  if (!diag) {
    float bL[4], bS1[4], bS2[4];
#pragma unroll
    for (int cf = 0; cf < 4; ++cf) { bL[cf] = 0.f; bS1[cf] = 0.f; bS2[cf] = 0.f; }
#pragma unroll
    for (int rf = 0; rf < 4; ++rf) {
      float4 tl[4];
#pragma unroll
      for (int cf = 0; cf < 4; ++cf)
        tl[cf] = *(const float4*)(labels +
                                  (size_t)(j0 + wc + cf * 16 + l15) * NN +
                                  i0 + wr + rf * 16 + quad * 4);
#pragma unroll
      for (int reg = 0; reg < 4; ++reg) {
        const int row_g = i0 + wr + rf * 16 + quad * 4 + reg;
        const float* lp = labels + (size_t)row_g * NN + j0 + wc + l15;
        float vL = 0.f, v1 = 0.f, v2 = 0.f;
#pragma unroll
        for (int cf = 0; cf < 4; ++cf) {
          const float s = acc[rf][cf][reg] * 5.0f;
          const float e = __expf(s);
          const float lbl = lp[cf * 16];
          vL += e; v1 += lbl * s; v2 += lbl;
          const float tlbl = (reg == 0)   ? tl[cf].x
                             : (reg == 1) ? tl[cf].y
                             : (reg == 2) ? tl[cf].z
                                          : tl[cf].w;
          bL[cf] += e; bS1[cf] += tlbl * s; bS2[cf] += tlbl;
        }
#pragma unroll
        for (int off = 1; off < 16; off <<= 1) {
          vL += __shfl_xor(vL, off, 64);
          v1 += __shfl_xor(v1, off, 64);
          v2 += __shfl_xor(v2, off, 64);
        }
        if (l15 == 0) {
          atomicAdd(&accL[row_g], vL);
          atomicAdd(&accS1[row_g], v1);
          atomicAdd(&accS2[row_g], v2);
        }
      }
    }
#pragma unroll
    for (int cf = 0; cf < 4; ++cf) {
      float vL = bL[cf], v1 = bS1[cf], v2 = bS2[cf];
      vL += __shfl_xor(vL, 16, 64); v1 += __shfl_xor(v1, 16, 64);
      v2 += __shfl_xor(v2, 16, 64);
      vL += __shfl_xor(vL, 32, 64); v1 += __shfl_xor(v1, 32, 64);
      v2 += __shfl_xor(v2, 32, 64);
      if (quad == 0) {
        const int c_g = j0 + wc + cf * 16 + l15;
        atomicAdd(&accL[c_g], vL);
        atomicAdd(&accS1[c_g], v1);
        atomicAdd(&accS2[c_g], v2);
      }
    }
  } else {
#pragma unroll
    for (int rf = 0; rf < 4; ++rf)
#pragma unroll
      for (int reg = 0; reg < 4; ++reg) {
        const int row_g = i0 + wr + rf * 16 + quad * 4 + reg;
        const float* lp = labels + (size_t)row_g * NN + j0 + wc + l15;
        float vL = 0.f, v1 = 0.f, v2 = 0.f;
#pragma unroll
        for (int cf = 0; cf < 4; ++cf) {
          const int col_g = j0 + wc + cf * 16 + l15;
          const float s = acc[rf][cf][reg] * 5.0f;
          const bool d = (row_g == col_g);
          const float e = d ? 0.f : __expf(s);
          const float lbl = d ? 0.f : lp[cf * 16];
          vL += e; v1 += lbl * s; v2 += lbl;
        }
#pragma unroll
        for (int off = 1; off < 16; off <<= 1) {
          vL += __shfl_xor(vL, off, 64);
          v1 += __shfl_xor(v1, off, 64);
          v2 += __shfl_xor(v2, off, 64);
        }
        if (l15 == 0) {
          atomicAdd(&accL[row_g], vL);
          atomicAdd(&accS1[row_g], v1);
          atomicAdd(&accS2[row_g], v2);
        }
      }
  }
}

// Kernel 3: loss = mean_i( S2_i*log(l_i) - S1_i )
__global__ __launch_bounds__(256) void finalize_kernel(
    const float* __restrict__ accL, const float* __restrict__ accS1,
    const float* __restrict__ accS2, float* __restrict__ out) {
  const int t = threadIdx.x;
  float sum = 0.f;
  for (int i = t; i < NN; i += 256)
    sum += accS2[i] * logf(accL[i]) - accS1[i];
#pragma unroll
  for (int off = 32; off > 0; off >>= 1) sum += __shfl_down(sum, off, 64);
  __shared__ float red[4];
  const int w = t >> 6, lane = t & 63;
  if (lane == 0) red[w] = sum;
  __syncthreads();
  if (t == 0) out[0] = (red[0] + red[1] + red[2] + red[3]) / (float)NN;
}

extern "C" void kernel_launch(void* const* d_in, const int* in_sizes, int n_in,
                              void* d_out, int out_size, void* d_ws,
                              size_t ws_size, hipStream_t stream) {
  const float* embs = (const float*)d_in[0];    // (8192,1024) fp32
  const float* labels = (const float*)d_in[1];  // (8192,8192) fp32
  float* out = (float*)d_out;

  // workspace: [0,16MB) bf16 X; 3 x 8192 fp32 accums; packed fp16 sim tiles
  unsigned short* xb = (unsigned short*)d_ws;
  char* p = (char*)d_ws + (size_t)NN * DD * 2;
  float* accL = (float*)p;
  float* accS1 = accL + NN;
  float* accS2 = accS1 + NN;
  _Float16* simb = (_Float16*)(p + 3 * NN * sizeof(float) + 128);
  const size_t need = (size_t)NN * DD * 2 + 3 * NN * sizeof(float) + 128 +
                      (size_t)NUT * 128 * 128 * sizeof(_Float16);

  normalize_kernel<<<NN, 256, 0, stream>>>(embs, xb, accL, accS1, accS2);
  if (ws_size >= need) {
    gemm_kernel<<<NUT, 256, 0, stream>>>(xb, simb);
    reduce_kernel<<<NUT, 256, 0, stream>>>(simb, labels, accL, accS1, accS2);
  } else {
    simloss_kernel<<<NUT, 256, 0, stream>>>(xb, labels, accL, accS1, accS2);
  }
  finalize_kernel<<<1, 256, 0, stream>>>(accL, accS1, accS2, out);
}

// Round 5
// 479.567 us; speedup vs baseline: 1.4190x; 1.1420x over previous
//
#include <hip/hip_runtime.h>
#include <hip/hip_bf16.h>

// Problem constants (reference: n=8192, d=1024, T=0.2, eps=1e-8)
#define NN 8192
#define DD 1024
#define NTILE 64           // 8192/128 tile blocks per dim
#define NUT (64 * 65 / 2)  // 2080 upper-tri tiles
#define SST 136            // sim-tile LDS row stride in shorts (16B-aligned pad)

typedef __attribute__((ext_vector_type(8))) short bf16x8;    // 8 bf16 = 4 VGPRs
typedef __attribute__((ext_vector_type(4))) float floatx4;   // MFMA C/D frag
typedef __attribute__((ext_vector_type(8))) _Float16 h16x8;  // 16B of fp16

__device__ __forceinline__ void load_lds16(const void* g, void* l) {
  // async global->LDS, 16B per lane; LDS dest = wave-uniform base + lane*16
  __builtin_amdgcn_global_load_lds(
      (const __attribute__((address_space(1))) unsigned int*)g,
      (__attribute__((address_space(3))) unsigned int*)l, 16, 0, 0);
}

__device__ __forceinline__ unsigned short f2bf(float x) {
  // round-to-nearest-even fp32 -> bf16
  unsigned int u = __float_as_uint(x);
  u = (u + 0x7fffu + ((u >> 16) & 1u)) >> 16;
  return (unsigned short)u;
}

// triangular decode: t -> (bi, bj), bi <= bj, row-major over bj
__device__ __forceinline__ void tri_decode(int t, int& bi, int& bj) {
  bi = (int)((129.0 - sqrt(129.0 * 129.0 - 8.0 * (double)t)) * 0.5);
  while (NTILE * (bi + 1) - ((bi + 1) * bi) / 2 <= t) ++bi;
  while (NTILE * bi - (bi * (bi - 1)) / 2 > t) --bi;
  bj = bi + (t - (NTILE * bi - (bi * (bi - 1)) / 2));
}

// Kernel 1: row L2-normalize + cast to bf16. One block per row.
// Also zero-inits the 3 per-row accumulators (replaces a memset dispatch).
__global__ __launch_bounds__(256) void normalize_kernel(
    const float* __restrict__ embs, unsigned short* __restrict__ xb,
    float* __restrict__ accL, float* __restrict__ accS1,
    float* __restrict__ accS2) {
  const int row = blockIdx.x;
  const int t = threadIdx.x;
  if (t == 0) { accL[row] = 0.f; accS1[row] = 0.f; accS2[row] = 0.f; }
  const float4 v = ((const float4*)(embs + (size_t)row * DD))[t];
  float ss = v.x * v.x + v.y * v.y + v.z * v.z + v.w * v.w;
#pragma unroll
  for (int off = 32; off > 0; off >>= 1) ss += __shfl_down(ss, off, 64);
  __shared__ float red[4];
  const int w = t >> 6, lane = t & 63;
  if (lane == 0) red[w] = ss;
  __syncthreads();
  const float tot = red[0] + red[1] + red[2] + red[3];
  const float rn = 1.0f / fmaxf(sqrtf(tot), 1e-8f);
  ushort4 o;
  o.x = f2bf(v.x * rn);
  o.y = f2bf(v.y * rn);
  o.z = f2bf(v.z * rn);
  o.w = f2bf(v.w * rn);
  ((ushort4*)(xb + (size_t)row * DD))[t] = o;
}

// Fused kernel: m97-structure GEMM (128x128, BK=64, XOR-swizzled staging,
// zero bank conflicts per R2) over upper-tri tiles; then the score tile is
// dumped to LDS (fp16, row stride SST=136 shorts -> 16B-aligned rows,
// bank-uniform for row-order b128 reads and col-order u16 reads), and both
// reduce passes (i-side rows, j-side cols) stream labels from HBM against
// the LDS tile. sim never touches HBM. Blocks in the label-stream phase
// overlap other blocks' MFMA phase (m114 co-scheduling).
__global__ __launch_bounds__(256) void fused_kernel(
    const unsigned short* __restrict__ xb, const float* __restrict__ labels,
    float* __restrict__ accL, float* __restrict__ accS1,
    float* __restrict__ accS2) {
  // 34816 B: [0,16KB) As, [16KB,32KB) Bs during K-loop; sim tile afterwards
  __shared__ __align__(16) unsigned short S[128 * SST];
  unsigned short* As = S;
  unsigned short* Bs = S + 128 * 64;
  _Float16* st = (_Float16*)S;

  int bi, bj;
  tri_decode(blockIdx.x, bi, bj);
  const bool diag = (bi == bj);
  const int i0 = bi * 128;
  const int j0 = bj * 128;

  const int tid = threadIdx.x;
  const int w = tid >> 6;
  const int lane = tid & 63;
  const int quad = lane >> 4;
  const int l15 = lane & 15;
  const int wr = (w >> 1) * 64;
  const int wc = (w & 1) * 64;

  const int schunk = w * 4;
  const int srow = lane >> 3;
  const int scol = ((lane & 7) ^ srow) * 8;  // staging XOR swizzle (R2)

  floatx4 acc[4][4];
#pragma unroll
  for (int a = 0; a < 4; ++a)
#pragma unroll
    for (int b = 0; b < 4; ++b) acc[a][b] = (floatx4){0.f, 0.f, 0.f, 0.f};

  for (int kt = 0; kt < 16; ++kt) {
    const int k0 = kt * 64;
#pragma unroll
    for (int it = 0; it < 4; ++it) {
      const int ch = schunk + it;
      load_lds16(xb + (size_t)(i0 + ch * 8 + srow) * DD + k0 + scol,
                 As + ch * 512);
      load_lds16(xb + (size_t)(j0 + ch * 8 + srow) * DD + k0 + scol,
                 Bs + ch * 512);
    }
    __syncthreads();

#pragma unroll
    for (int kf = 0; kf < 2; ++kf) {
      bf16x8 af[4], bfr[4];
      const int pg = ((kf * 4 + quad) ^ (l15 & 7)) * 8;
#pragma unroll
      for (int rf = 0; rf < 4; ++rf)
        af[rf] = *(const bf16x8*)(As + (wr + rf * 16 + l15) * 64 + pg);
#pragma unroll
      for (int cf = 0; cf < 4; ++cf)
        bfr[cf] = *(const bf16x8*)(Bs + (wc + cf * 16 + l15) * 64 + pg);
#pragma unroll
      for (int rf = 0; rf < 4; ++rf)
#pragma unroll
        for (int cf = 0; cf < 4; ++cf)
          acc[rf][cf] = __builtin_amdgcn_mfma_f32_16x16x32_bf16(
              af[rf], bfr[cf], acc[rf][cf], 0, 0, 0);
    }
    __syncthreads();  // also guards the LDS reuse below
  }

  // acc -> LDS sim tile (scaled by 1/T = 5). C/D layout: col = l15,
  // row = quad*4 + reg (m89/m91). u16 scatter writes; quads 0&2 / 1&3
  // alias banks (4-way, ~1.6x on a cheap op).
#pragma unroll
  for (int rf = 0; rf < 4; ++rf)
#pragma unroll
    for (int cf = 0; cf < 4; ++cf) {
      const int col = wc + cf * 16 + l15;
#pragma unroll
      for (int reg = 0; reg < 4; ++reg) {
        const int row = wr + rf * 16 + quad * 4 + reg;
        st[row * SST + col] = (_Float16)(acc[rf][cf][reg] * 5.0f);
      }
    }
  __syncthreads();

  // ---- pass 1: i-side rows. thread t -> row r = t>>1, col half (t&1)*64.
  {
    const int r = tid >> 1;
    const int ch = (tid & 1) * 64;
    float vL = 0.f, v1 = 0.f, v2 = 0.f;
    const float4* lrow =
        (const float4*)(labels + (size_t)(i0 + r) * NN + j0 + ch);
    const _Float16* srow = st + r * SST + ch;
#pragma unroll
    for (int g = 0; g < 8; ++g) {
      const h16x8 sv = *(const h16x8*)(srow + g * 8);  // 16B, bank-uniform
      const float4 l0 = lrow[2 * g];
      const float4 l1 = lrow[2 * g + 1];
      const float ls[8] = {l0.x, l0.y, l0.z, l0.w, l1.x, l1.y, l1.z, l1.w};
#pragma unroll
      for (int e = 0; e < 8; ++e) {
        const int c = ch + g * 8 + e;
        const float s = (float)sv[e];
        const bool d = diag && (c == r);
        vL += d ? 0.f : __expf(s);
        const float lb = d ? 0.f : ls[e];
        v1 += lb * s;
        v2 += lb;
      }
    }
    vL += __shfl_xor(vL, 1, 64);
    v1 += __shfl_xor(v1, 1, 64);
    v2 += __shfl_xor(v2, 1, 64);
    if (!(tid & 1)) {
      atomicAdd(&accL[i0 + r], vL);
      atomicAdd(&accS1[i0 + r], v1);
      atomicAdd(&accS2[i0 + r], v2);
    }
  }

  // ---- pass 2: j-side cols (off-diag only). thread t -> col c = t&127,
  // row half (t>>7)*64. Labels[j0+c][i0+...] contiguous per thread; sim
  // read col-order from LDS (u16, lanes span 128B -> 2 lanes/bank, free).
  if (!diag) {
    const int c = tid & 127;
    const int rb = (tid >> 7) * 64;
    float vL = 0.f, v1 = 0.f, v2 = 0.f;
    const float4* lrow =
        (const float4*)(labels + (size_t)(j0 + c) * NN + i0 + rb);
#pragma unroll 4
    for (int kk = 0; kk < 16; ++kk) {
      const float4 lb4 = lrow[kk];
      const float ls[4] = {lb4.x, lb4.y, lb4.z, lb4.w};
#pragma unroll
      for (int e = 0; e < 4; ++e) {
        const int rr = rb + kk * 4 + e;
        const float s = (float)st[rr * SST + c];
        vL += __expf(s);
        v1 += ls[e] * s;
        v2 += ls[e];
      }
    }
    atomicAdd(&accL[j0 + c], vL);
    atomicAdd(&accS1[j0 + c], v1);
    atomicAdd(&accS2[j0 + c], v2);
  }
}

// Kernel 3: loss = mean_i( S2_i*log(l_i) - S1_i )
__global__ __launch_bounds__(256) void finalize_kernel(
    const float* __restrict__ accL, const float* __restrict__ accS1,
    const float* __restrict__ accS2, float* __restrict__ out) {
  const int t = threadIdx.x;
  float sum = 0.f;
  for (int i = t; i < NN; i += 256)
    sum += accS2[i] * logf(accL[i]) - accS1[i];
#pragma unroll
  for (int off = 32; off > 0; off >>= 1) sum += __shfl_down(sum, off, 64);
  __shared__ float red[4];
  const int w = t >> 6, lane = t & 63;
  if (lane == 0) red[w] = sum;
  __syncthreads();
  if (t == 0) out[0] = (red[0] + red[1] + red[2] + red[3]) / (float)NN;
}

extern "C" void kernel_launch(void* const* d_in, const int* in_sizes, int n_in,
                              void* d_out, int out_size, void* d_ws,
                              size_t ws_size, hipStream_t stream) {
  const float* embs = (const float*)d_in[0];    // (8192,1024) fp32
  const float* labels = (const float*)d_in[1];  // (8192,8192) fp32
  float* out = (float*)d_out;

  // workspace: [0,16MB) bf16 normalized X; then 3 x 8192 fp32 row accums
  unsigned short* xb = (unsigned short*)d_ws;
  float* accL = (float*)((char*)d_ws + (size_t)NN * DD * 2);
  float* accS1 = accL + NN;
  float* accS2 = accS1 + NN;

  normalize_kernel<<<NN, 256, 0, stream>>>(embs, xb, accL, accS1, accS2);
  fused_kernel<<<NUT, 256, 0, stream>>>(xb, labels, accL, accS1, accS2);
  finalize_kernel<<<1, 256, 0, stream>>>(accL, accS1, accS2, out);
}

// Round 6
// 416.606 us; speedup vs baseline: 1.6335x; 1.1511x over previous
//
#include <hip/hip_runtime.h>
#include <hip/hip_bf16.h>

// Problem constants (reference: n=8192, d=1024, T=0.2, eps=1e-8)
#define NN 8192
#define DD 1024
#define NTILE 64           // 8192/128 tile blocks per dim
#define NUT (64 * 65 / 2)  // 2080 upper-tri tiles
#define SST 136            // sim-tile LDS row stride in shorts (16B-aligned pad)

typedef __attribute__((ext_vector_type(4))) int i32x4;
typedef __attribute__((ext_vector_type(8))) int i32x8;       // 32B fp8 MFMA operand
typedef __attribute__((ext_vector_type(4))) float floatx4;   // MFMA C/D frag
typedef __attribute__((ext_vector_type(8))) _Float16 h16x8;  // 16B of fp16

__device__ __forceinline__ void load_lds16(const void* g, void* l) {
  // async global->LDS, 16B per lane; LDS dest = wave-uniform base + lane*16
  __builtin_amdgcn_global_load_lds(
      (const __attribute__((address_space(1))) unsigned int*)g,
      (__attribute__((address_space(3))) unsigned int*)l, 16, 0, 0);
}

// triangular decode: t -> (bi, bj), bi <= bj, row-major over bj
__device__ __forceinline__ void tri_decode(int t, int& bi, int& bj) {
  bi = (int)((129.0 - sqrt(129.0 * 129.0 - 8.0 * (double)t)) * 0.5);
  while (NTILE * (bi + 1) - ((bi + 1) * bi) / 2 <= t) ++bi;
  while (NTILE * bi - (bi * (bi - 1)) / 2 > t) --bi;
  bj = bi + (t - (NTILE * bi - (bi * (bi - 1)) / 2));
}

// Kernel 1: row L2-normalize, scale by 16, cast to fp8 e4m3 (packed 4/thread).
// Scale 16 centers unit-norm components (~1/32) in e4m3's range; the GEMM
// result is then 256*sim, rescaled by 5/256 in the epilogue.
// Also zero-inits the 3 per-row accumulators.
__global__ __launch_bounds__(256) void normalize_kernel(
    const float* __restrict__ embs, unsigned int* __restrict__ xq,
    float* __restrict__ accL, float* __restrict__ accS1,
    float* __restrict__ accS2) {
  const int row = blockIdx.x;
  const int t = threadIdx.x;
  if (t == 0) { accL[row] = 0.f; accS1[row] = 0.f; accS2[row] = 0.f; }
  const float4 v = ((const float4*)(embs + (size_t)row * DD))[t];
  float ss = v.x * v.x + v.y * v.y + v.z * v.z + v.w * v.w;
#pragma unroll
  for (int off = 32; off > 0; off >>= 1) ss += __shfl_down(ss, off, 64);
  __shared__ float red[4];
  const int w = t >> 6, lane = t & 63;
  if (lane == 0) red[w] = ss;
  __syncthreads();
  const float tot = red[0] + red[1] + red[2] + red[3];
  const float rn = 16.0f / fmaxf(sqrtf(tot), 1e-8f);
  int p = __builtin_amdgcn_cvt_pk_fp8_f32(v.x * rn, v.y * rn, 0, false);
  p = __builtin_amdgcn_cvt_pk_fp8_f32(v.z * rn, v.w * rn, p, true);
  xq[row * 256 + t] = (unsigned int)p;
}

// Fused kernel: MX-FP8 GEMM (128x128 tile, BK=128, 8 kt) over upper-tri
// tiles via mfma_scale_f32_16x16x128_f8f6f4 with unit scales (E8M0 0x7F);
// then the score tile goes to LDS fp16 (stride SST) and both reduce passes
// (i-side rows, j-side cols) stream labels from HBM against the LDS tile.
// LDS XOR-swizzle: 128B row-slice = 8 x 16B groups; phys group p of row r
// holds logical group p ^ (r&7) (applied on the global source at staging,
// undone at ds_read; read aliasing <=2-way = free per m136).
__global__ __launch_bounds__(256) void fused_kernel(
    const unsigned char* __restrict__ xq, const float* __restrict__ labels,
    float* __restrict__ accL, float* __restrict__ accS1,
    float* __restrict__ accS2) {
  // 34816 B: [0,16KB) As, [16KB,32KB) Bs during K-loop; sim tile afterwards
  __shared__ __align__(16) unsigned short S[128 * SST];
  unsigned char* As8 = (unsigned char*)S;
  unsigned char* Bs8 = As8 + 16384;
  _Float16* st = (_Float16*)S;

  int bi, bj;
  tri_decode(blockIdx.x, bi, bj);
  const bool diag = (bi == bj);
  const int i0 = bi * 128;
  const int j0 = bj * 128;

  const int tid = threadIdx.x;
  const int w = tid >> 6;
  const int lane = tid & 63;
  const int quad = lane >> 4;
  const int l15 = lane & 15;
  const int wr = (w >> 1) * 64;
  const int wc = (w & 1) * 64;

  // staging: 16 chunks of 8 rows x 128B per buffer; each wave does 4 A + 4 B
  const int schunk = w * 4;
  const int srow = lane >> 3;                       // 0..7 row within chunk
  const int scol = ((lane & 7) ^ srow) << 4;        // swizzled 16B src group

  floatx4 acc[4][4];
#pragma unroll
  for (int a = 0; a < 4; ++a)
#pragma unroll
    for (int b = 0; b < 4; ++b) acc[a][b] = (floatx4){0.f, 0.f, 0.f, 0.f};

  for (int kt = 0; kt < 8; ++kt) {
    const int k0 = kt * 128;
#pragma unroll
    for (int it = 0; it < 4; ++it) {
      const int ch = schunk + it;
      load_lds16(xq + (size_t)(i0 + ch * 8 + srow) * DD + k0 + scol,
                 As8 + ch * 1024);
      load_lds16(xq + (size_t)(j0 + ch * 8 + srow) * DD + k0 + scol,
                 Bs8 + ch * 1024);
    }
    __syncthreads();  // drains vmcnt for global_load_lds

    const int m7 = l15 & 7;
    i32x8 bfr[4];
#pragma unroll
    for (int cf = 0; cf < 4; ++cf) {
      const unsigned char* bb = Bs8 + (wc + cf * 16 + l15) * 128;
      const i32x4 lo = *(const i32x4*)(bb + (((2 * quad) ^ m7) << 4));
      const i32x4 hi = *(const i32x4*)(bb + (((2 * quad + 1) ^ m7) << 4));
      bfr[cf] = __builtin_shufflevector(lo, hi, 0, 1, 2, 3, 4, 5, 6, 7);
    }
#pragma unroll
    for (int rf = 0; rf < 4; ++rf) {
      const unsigned char* ab = As8 + (wr + rf * 16 + l15) * 128;
      const i32x4 lo = *(const i32x4*)(ab + (((2 * quad) ^ m7) << 4));
      const i32x4 hi = *(const i32x4*)(ab + (((2 * quad + 1) ^ m7) << 4));
      const i32x8 af = __builtin_shufflevector(lo, hi, 0, 1, 2, 3, 4, 5, 6, 7);
#pragma unroll
      for (int cf = 0; cf < 4; ++cf)
        acc[rf][cf] = __builtin_amdgcn_mfma_scale_f32_16x16x128_f8f6f4(
            af, bfr[cf], acc[rf][cf], 0, 0,  // cbsz/blgp: FP8 e4m3 both
            0, 0x7F7F7F7F,                   // scale A: opsel 0, E8M0 = 1.0
            0, 0x7F7F7F7F);                  // scale B
    }
    __syncthreads();  // also guards the LDS reuse below
  }

  // acc -> LDS sim tile, s = acc * 5/256 (fp8 scale 16*16 + 1/T). C/D
  // layout: col = l15, row = quad*4 + reg (m89/m91, shape-determined).
#pragma unroll
  for (int rf = 0; rf < 4; ++rf)
#pragma unroll
    for (int cf = 0; cf < 4; ++cf) {
      const int col = wc + cf * 16 + l15;
#pragma unroll
      for (int reg = 0; reg < 4; ++reg) {
        const int row = wr + rf * 16 + quad * 4 + reg;
        st[row * SST + col] = (_Float16)(acc[rf][cf][reg] * 0.01953125f);
      }
    }
  __syncthreads();

  // ---- pass 1: i-side rows. thread t -> row r = t>>1, col half (t&1)*64.
  {
    const int r = tid >> 1;
    const int ch = (tid & 1) * 64;
    float vL = 0.f, v1 = 0.f, v2 = 0.f;
    const float4* lrow =
        (const float4*)(labels + (size_t)(i0 + r) * NN + j0 + ch);
    const _Float16* srow = st + r * SST + ch;
#pragma unroll
    for (int g = 0; g < 8; ++g) {
      const h16x8 sv = *(const h16x8*)(srow + g * 8);  // 16B, bank-uniform
      const float4 l0 = lrow[2 * g];
      const float4 l1 = lrow[2 * g + 1];
      const float ls[8] = {l0.x, l0.y, l0.z, l0.w, l1.x, l1.y, l1.z, l1.w};
#pragma unroll
      for (int e = 0; e < 8; ++e) {
        const int c = ch + g * 8 + e;
        const float s = (float)sv[e];
        const bool d = diag && (c == r);
        vL += d ? 0.f : __expf(s);
        const float lb = d ? 0.f : ls[e];
        v1 += lb * s;
        v2 += lb;
      }
    }
    vL += __shfl_xor(vL, 1, 64);
    v1 += __shfl_xor(v1, 1, 64);
    v2 += __shfl_xor(v2, 1, 64);
    if (!(tid & 1)) {
      atomicAdd(&accL[i0 + r], vL);
      atomicAdd(&accS1[i0 + r], v1);
      atomicAdd(&accS2[i0 + r], v2);
    }
  }

  // ---- pass 2: j-side cols (off-diag only). thread t -> col c = t&127,
  // row half (t>>7)*64. Labels[j0+c][i0+...] contiguous per thread; sim
  // read col-order from LDS (u16, 2 lanes/bank, free).
  if (!diag) {
    const int c = tid & 127;
    const int rb = (tid >> 7) * 64;
    float vL = 0.f, v1 = 0.f, v2 = 0.f;
    const float4* lrow =
        (const float4*)(labels + (size_t)(j0 + c) * NN + i0 + rb);
#pragma unroll 4
    for (int kk = 0; kk < 16; ++kk) {
      const float4 lb4 = lrow[kk];
      const float ls[4] = {lb4.x, lb4.y, lb4.z, lb4.w};
#pragma unroll
      for (int e = 0; e < 4; ++e) {
        const int rr = rb + kk * 4 + e;
        const float s = (float)st[rr * SST + c];
        vL += __expf(s);
        v1 += ls[e] * s;
        v2 += ls[e];
      }
    }
    atomicAdd(&accL[j0 + c], vL);
    atomicAdd(&accS1[j0 + c], v1);
    atomicAdd(&accS2[j0 + c], v2);
  }
}

// Kernel 3: loss = mean_i( S2_i*log(l_i) - S1_i )
__global__ __launch_bounds__(256) void finalize_kernel(
    const float* __restrict__ accL, const float* __restrict__ accS1,
    const float* __restrict__ accS2, float* __restrict__ out) {
  const int t = threadIdx.x;
  float sum = 0.f;
  for (int i = t; i < NN; i += 256)
    sum += accS2[i] * logf(accL[i]) - accS1[i];
#pragma unroll
  for (int off = 32; off > 0; off >>= 1) sum += __shfl_down(sum, off, 64);
  __shared__ float red[4];
  const int w = t >> 6, lane = t & 63;
  if (lane == 0) red[w] = sum;
  __syncthreads();
  if (t == 0) out[0] = (red[0] + red[1] + red[2] + red[3]) / (float)NN;
}

extern "C" void kernel_launch(void* const* d_in, const int* in_sizes, int n_in,
                              void* d_out, int out_size, void* d_ws,
                              size_t ws_size, hipStream_t stream) {
  const float* embs = (const float*)d_in[0];    // (8192,1024) fp32
  const float* labels = (const float*)d_in[1];  // (8192,8192) fp32
  float* out = (float*)d_out;

  // workspace: [0,8MB) fp8 normalized X (x16); then 3 x 8192 fp32 accums
  unsigned int* xq = (unsigned int*)d_ws;
  float* accL = (float*)((char*)d_ws + (size_t)NN * DD);
  float* accS1 = accL + NN;
  float* accS2 = accS1 + NN;

  normalize_kernel<<<NN, 256, 0, stream>>>(embs, xq, accL, accS1, accS2);
  fused_kernel<<<NUT, 256, 0, stream>>>((const unsigned char*)xq, labels,
                                        accL, accS1, accS2);
  finalize_kernel<<<1, 256, 0, stream>>>(accL, accS1, accS2, out);
}